// Round 16
// baseline (59.748 us; speedup 1.0000x reference)
//
#include <hip/hip_runtime.h>
#include <hip/hip_bf16.h>

typedef __bf16 bf16x8 __attribute__((ext_vector_type(8)));
typedef float f32x4 __attribute__((ext_vector_type(4)));

#define G 8
#define B 32
#define D 32
#define O 32
#define K 4096   // N*T (floats per W row)
#define T 64
#define KSPLIT 8
#define KCH (K / KSPLIT)      // 512 floats per wave
#define NKT (KCH / 32)        // 16 k-tiles of 32

// ws: XB bf16 [K/32][B][32] = 256 KB only.
#define XB_ELEMS (B * K)

// Fused prep: threads [0,16384) build XB (MFMA B-frag order, no mask);
// threads [16384, 49152) init out[b][d][o] = bias[d][o] (gemm atomically adds).
__global__ __launch_bounds__(256) void prep_and_init(const float* __restrict__ x,
                                                     const float* __restrict__ bias,
                                                     __bf16* __restrict__ xb,
                                                     float* __restrict__ out) {
    int tid = blockIdx.x * 256 + threadIdx.x;
    if (tid < 16384) {
        int b = (tid >> 2) & 31;
        int k = (tid >> 7) * 32 + (tid & 3) * 8;
        const float4 x0 = *(const float4*)(x + b * K + k);
        const float4 x1 = *(const float4*)(x + b * K + k + 4);
        bf16x8 r;
        r[0] = (__bf16)x0.x; r[1] = (__bf16)x0.y; r[2] = (__bf16)x0.z; r[3] = (__bf16)x0.w;
        r[4] = (__bf16)x1.x; r[5] = (__bf16)x1.y; r[6] = (__bf16)x1.z; r[7] = (__bf16)x1.w;
        *(bf16x8*)(xb + (size_t)tid * 8) = r;   // flat idx == tid*8: coalesced
    } else {
        int t2 = tid - 16384;           // 32768 = B*D*O, out flat = b*1024 + d*32 + o
        out[t2] = bias[t2 & 1023];
    }
}

// "Probe + MFMA": NO LDS, NO barriers, NO waitcnt choreography.
// Block = ONE WAVE (d, g, oh, ks): 16 o-rows x 32 b over a K/8 slice (512 k).
// Each lane loads its MFMA A-fragment DIRECTLY from global: lane (l15,g16)
// reads W[row = oh*16+l15][k = ktile*32 + g16*8 + j] as 2x dwordx4; the
// instruction pair covers 128B contiguous per row. xb B-fragments load
// direct from the L2-hot 256KB XB. mask applied to A before bf16 convert.
// 3-deep register ring (sets S0..S2, static indices): load k-tile t+2 while
// computing t -> ~8 loads (8KB/wave) in flight continuously; 4096 waves =
// 16/CU -> ~128KB/CU in flight = R13-probe level (which measured 7.3 TB/s).
// Epilogue: out[b][d][o] += y[b][g]*acc (unsafeAtomicAdd, L2-resident 128KB).
__global__ __launch_bounds__(64, 4) void gemm_main(const float* __restrict__ W,
                                                   const __bf16* __restrict__ xb,
                                                   const float* __restrict__ mask,
                                                   const float* __restrict__ y,
                                                   float* __restrict__ out) {
    const int d = blockIdx.x, g = blockIdx.y;
    const int oh = blockIdx.z & 1, ks = blockIdx.z >> 1;   // ks in 0..7
    const int lane = threadIdx.x;
    const int l15 = lane & 15, g16 = lane >> 4;

    // mask row o = oh*16 + l15; lane needs t = (ktl&1)*32 + g16*8 + j
    const float* mrow = mask + (oh * 16 + l15) * T + g16 * 8;
    const float4 me0 = *(const float4*)(mrow);
    const float4 me1 = *(const float4*)(mrow + 4);
    const float4 mo0 = *(const float4*)(mrow + 32);
    const float4 mo1 = *(const float4*)(mrow + 36);

    // W per-lane fragment base: row = oh*16+l15, k-offset = ks*KCH + g16*8
    const float* wl = W + ((size_t)(g * D + d) * O + oh * 16 + l15) * K
                        + ks * KCH + g16 * 8;
    // XB per-lane bases: elem = (ks*NKT + ktl)*1024 + b*32 + g16*8
    const __bf16* xL = xb + (size_t)(ks * NKT) * 1024 + l15 * 32 + g16 * 8;
    const __bf16* xH = xL + 512;   // b + 16

    f32x4 accL = {0.f, 0.f, 0.f, 0.f};
    f32x4 accH = {0.f, 0.f, 0.f, 0.f};

    // 3-deep ring register sets (all statically indexed)
    f32x4 w0_0, w1_0, w0_1, w1_1, w0_2, w1_2;
    bf16x8 xl_0, xh_0, xl_1, xh_1, xl_2, xh_2;

#define LOADSET(p, ktl)                                                           \
    {                                                                             \
        w0_##p = *(const f32x4*)(wl + (ktl) * 32);                                \
        w1_##p = *(const f32x4*)(wl + (ktl) * 32 + 4);                            \
        xl_##p = *(const bf16x8*)(xL + (size_t)(ktl) * 1024);                     \
        xh_##p = *(const bf16x8*)(xH + (size_t)(ktl) * 1024);                     \
    }
#define COMP(p, ktl)                                                              \
    {                                                                             \
        const float4 ms0 = ((ktl) & 1) ? mo0 : me0;                               \
        const float4 ms1 = ((ktl) & 1) ? mo1 : me1;                               \
        bf16x8 af;                                                                \
        af[0] = (__bf16)(w0_##p[0] * ms0.x); af[1] = (__bf16)(w0_##p[1] * ms0.y); \
        af[2] = (__bf16)(w0_##p[2] * ms0.z); af[3] = (__bf16)(w0_##p[3] * ms0.w); \
        af[4] = (__bf16)(w1_##p[0] * ms1.x); af[5] = (__bf16)(w1_##p[1] * ms1.y); \
        af[6] = (__bf16)(w1_##p[2] * ms1.z); af[7] = (__bf16)(w1_##p[3] * ms1.w); \
        accL = __builtin_amdgcn_mfma_f32_16x16x32_bf16(af, xl_##p, accL, 0, 0, 0);\
        accH = __builtin_amdgcn_mfma_f32_16x16x32_bf16(af, xh_##p, accH, 0, 0, 0);\
    }

    LOADSET(0, 0)
    LOADSET(1, 1)
    LOADSET(2, 2)  COMP(0, 0)
    LOADSET(0, 3)  COMP(1, 1)
    LOADSET(1, 4)  COMP(2, 2)
    LOADSET(2, 5)  COMP(0, 3)
    LOADSET(0, 6)  COMP(1, 4)
    LOADSET(1, 7)  COMP(2, 5)
    LOADSET(2, 8)  COMP(0, 6)
    LOADSET(0, 9)  COMP(1, 7)
    LOADSET(1, 10) COMP(2, 8)
    LOADSET(2, 11) COMP(0, 9)
    LOADSET(0, 12) COMP(1, 10)
    LOADSET(1, 13) COMP(2, 11)
    LOADSET(2, 14) COMP(0, 12)
    LOADSET(0, 15) COMP(1, 13)
    COMP(2, 14)
    COMP(0, 15)
#undef LOADSET
#undef COMP

    // C/D: lane holds D[row=g16*4+i][col=l15]; row = o-local, col = b-local
    const float yv0 = y[l15 * G + g];
    const float yv1 = y[(16 + l15) * G + g];
    float* op0 = out + l15 * (D * O) + d * O + oh * 16 + g16 * 4;
    float* op1 = op0 + 16 * (D * O);
    #pragma unroll
    for (int i = 0; i < 4; ++i) {
        unsafeAtomicAdd(op0 + i, yv0 * accL[i]);
        unsafeAtomicAdd(op1 + i, yv1 * accH[i]);
    }
}

extern "C" void kernel_launch(void* const* d_in, const int* in_sizes, int n_in,
                              void* d_out, int out_size, void* d_ws, size_t ws_size,
                              hipStream_t stream) {
    const float* x    = (const float*)d_in[0];
    const float* y    = (const float*)d_in[1];
    const float* w    = (const float*)d_in[2];
    const float* bias = (const float*)d_in[3];
    const float* mask = (const float*)d_in[4];
    float* out = (float*)d_out;

    __bf16* xbp = (__bf16*)d_ws;

    prep_and_init<<<192, 256, 0, stream>>>(x, bias, xbp, out);
    gemm_main<<<dim3(D, G, 16), 64, 0, stream>>>(w, xbp, mask, y, out);
}